// Round 3
// baseline (215.737 us; speedup 1.0000x reference)
//
#include <hip/hip_runtime.h>

// RoiCut: out[i, c, y, x] = fm[assoc[i], c, y0_i + y, x0_i + x]
// fm: [8, 256, 200, 200] fp32, boxes_yx: [512, 2] int32 (y0, x0), assoc: [512] int32
// out: [512, 256, 32, 32] fp32
//
// R2 strategy:
//  - boxes sorted by (assoc, y0, x0) so overlapping boxes are adjacent (1-block sort)
//  - block order: channel-group OUTER, sorted-box INNER -> instantaneous read
//    working set = 8 samples x 4 planes ~= 5 MB, reuse distance ~1 block (L2 hits)
//  - non-temporal stores: the 512 MB write stream must not evict read lines from L2/L3
//  - 4 channels per block to amortize scalar setup and add load ILP

typedef float v4f __attribute__((ext_vector_type(4)));

constexpr int C_   = 256;
constexpr int H_   = 200;
constexpr int W_   = 200;
constexpr int BOX_ = 32;
constexpr int N_   = 512;
constexpr int CPB_ = 4;   // channels per block

__global__ __launch_bounds__(512) void sort_boxes_kernel(
    const int* __restrict__ boxes,
    const int* __restrict__ assoc,
    int*       __restrict__ perm)
{
    __shared__ unsigned int key[N_];
    int t = threadIdx.x;  // 512 threads, one per box

    int y0 = boxes[2 * t];
    int x0 = boxes[2 * t + 1];
    y0 = min(max(y0, 0), H_ - BOX_);
    x0 = min(max(x0, 0), W_ - BOX_);
    unsigned int a = (unsigned int)assoc[t];
    // key: [assoc:3 | y0:8 | x0:8 | idx:9]  -- unique keys -> deterministic sort
    key[t] = (a << 25) | ((unsigned int)y0 << 17) | ((unsigned int)x0 << 9) | (unsigned int)t;
    __syncthreads();

    for (int k = 2; k <= N_; k <<= 1) {
        for (int j = k >> 1; j > 0; j >>= 1) {
            int ixj = t ^ j;
            if (ixj > t) {
                unsigned int va = key[t], vb = key[ixj];
                bool asc = ((t & k) == 0);
                if ((va > vb) == asc) { key[t] = vb; key[ixj] = va; }
            }
            __syncthreads();
        }
    }

    perm[t] = (int)(key[t] & 511u);
}

__global__ __launch_bounds__(256) void roicut_kernel(
    const float* __restrict__ fm,
    const int*   __restrict__ boxes,
    const int*   __restrict__ assoc,
    const int*   __restrict__ perm,
    float*       __restrict__ out)
{
    int b = blockIdx.x;
    int s = b & (N_ - 1);   // sorted box slot (INNER)
    int g = b >> 9;         // channel group 0..63 (OUTER)
    int t = threadIdx.x;    // 256 threads cover 32x32 crop, 4 floats each

    int i  = perm[s];       // actual box index (uniform per block -> scalar)
    int a  = assoc[i];
    int y0 = boxes[2 * i];
    int x0 = boxes[2 * i + 1];
    y0 = min(max(y0, 0), H_ - BOX_);
    x0 = min(max(x0, 0), W_ - BOX_);

    int y = t >> 3;            // 0..31
    int x = (t & 7) << 2;      // 0,4,...,28

    int c0 = g * CPB_;
    const float* src0 = fm + ((((size_t)a * C_ + c0) * H_ + (y0 + y)) * W_ + (x0 + x));
    float*       dst0 = out + (((size_t)i << 18) + ((size_t)c0 << 10) + ((size_t)t << 2));

    // gather 4 channels first (load ILP), then stream out non-temporally
    v4f v[CPB_];
    #pragma unroll
    for (int j = 0; j < CPB_; ++j) {
        const float* src = src0 + (size_t)j * (H_ * W_);
        v[j][0] = src[0];
        v[j][1] = src[1];
        v[j][2] = src[2];
        v[j][3] = src[3];
    }
    #pragma unroll
    for (int j = 0; j < CPB_; ++j) {
        __builtin_nontemporal_store(v[j], reinterpret_cast<v4f*>(dst0 + (j << 10)));
    }
}

extern "C" void kernel_launch(void* const* d_in, const int* in_sizes, int n_in,
                              void* d_out, int out_size, void* d_ws, size_t ws_size,
                              hipStream_t stream) {
    const float* fm    = (const float*)d_in[0];
    const int*   boxes = (const int*)d_in[1];
    const int*   assoc = (const int*)d_in[2];
    float*       out   = (float*)d_out;
    int*         perm  = (int*)d_ws;   // 512 ints

    sort_boxes_kernel<<<1, N_, 0, stream>>>(boxes, assoc, perm);

    int grid = N_ * (C_ / CPB_);  // 32768 blocks: box-inner, channel-group-outer
    roicut_kernel<<<grid, 256, 0, stream>>>(fm, boxes, assoc, perm, out);
}

// Round 4
// 173.363 us; speedup vs baseline: 1.2444x; 1.2444x over previous
//
#include <hip/hip_runtime.h>

// RoiCut: out[i, c, y, x] = fm[assoc[i], c, y0_i + y, x0_i + x]
// fm: [8, 256, 200, 200] fp32, boxes_yx: [512, 2] int32 (y0, x0), assoc: [512] int32
// out: [512, 256, 32, 32] fp32
//
// R3 strategy: structural exact-once reads.
//  - block = (sample, channel); whole 160,000 B plane staged into dynamic LDS
//    with perfectly coalesced float4 loads -> HBM reads = 327 MB, fetched once,
//    no cache dependence, no misalignment over-fetch.
//  - sort kernel groups boxes by sample (keys carry clipped y0/x0 + box idx).
//  - box loop: 4 boxes in flight (wave-uniform sub), 4x ds_read_b32 (<=2-way
//    bank aliasing = free) + 1 non-temporal dwordx4 store per thread.
//  - writes non-temporal: the 512 MB write stream never touches what matters.

typedef float v4f __attribute__((ext_vector_type(4)));

constexpr int C_    = 256;
constexpr int H_    = 200;
constexpr int W_    = 200;
constexpr int BOX_  = 32;
constexpr int N_    = 512;
constexpr int B_    = 8;
constexpr int PLANE  = H_ * W_;    // 40000 floats
constexpr int PLANE4 = PLANE / 4;  // 10000 float4

__global__ __launch_bounds__(512) void sort_boxes_kernel(
    const int* __restrict__ boxes,
    const int* __restrict__ assoc,
    unsigned int* __restrict__ keys,
    int* __restrict__ starts)
{
    __shared__ unsigned int key[N_];
    int t = threadIdx.x;  // 512 threads, one per box

    int y0 = boxes[2 * t];
    int x0 = boxes[2 * t + 1];
    y0 = min(max(y0, 0), H_ - BOX_);
    x0 = min(max(x0, 0), W_ - BOX_);
    unsigned int a = (unsigned int)assoc[t];
    // key: [assoc:3 | y0:8 | x0:8 | idx:9] -- unique -> deterministic sort
    key[t] = (a << 25) | ((unsigned int)y0 << 17) | ((unsigned int)x0 << 9) | (unsigned int)t;
    __syncthreads();

    for (int k = 2; k <= N_; k <<= 1) {
        for (int j = k >> 1; j > 0; j >>= 1) {
            int ixj = t ^ j;
            if (ixj > t) {
                unsigned int va = key[t], vb = key[ixj];
                bool asc = ((t & k) == 0);
                if ((va > vb) == asc) { key[t] = vb; key[ixj] = va; }
            }
            __syncthreads();
        }
    }

    unsigned int v = key[t];
    keys[t] = v;
    int at = (int)(v >> 25);
    int ap = (t == 0) ? -1 : (int)(key[t - 1] >> 25);
    for (int aa = ap + 1; aa <= at; ++aa) starts[aa] = t;           // handles empty samples
    if (t == N_ - 1) for (int aa = at + 1; aa <= B_; ++aa) starts[aa] = N_;
}

__global__ __launch_bounds__(1024) void roicut_kernel(
    const float* __restrict__ fm,
    const unsigned int* __restrict__ keys,
    const int* __restrict__ starts,
    float* __restrict__ out)
{
    extern __shared__ float lds[];   // 160,000 B = one plane

    int bid = blockIdx.x;
    int a = bid >> 8;       // sample
    int c = bid & 255;      // channel
    int t = threadIdx.x;    // 1024 threads

    // ---- stage whole plane (a, c) into LDS, perfectly coalesced ----
    const v4f* src = (const v4f*)(fm + (size_t)(a * C_ + c) * PLANE);
    v4f* l4 = (v4f*)lds;
    v4f r0 = src[t];
    v4f r1 = src[t + 1024];
    v4f r2 = src[t + 2048];
    v4f r3 = src[t + 3072];
    v4f r4 = src[t + 4096];
    v4f r5 = src[t + 5120];
    v4f r6 = src[t + 6144];
    v4f r7 = src[t + 7168];
    v4f r8 = src[t + 8192];
    bool tail = (t + 9216) < PLANE4;   // t < 784
    v4f r9;
    if (tail) r9 = src[t + 9216];
    l4[t]        = r0;
    l4[t + 1024] = r1;
    l4[t + 2048] = r2;
    l4[t + 3072] = r3;
    l4[t + 4096] = r4;
    l4[t + 5120] = r5;
    l4[t + 6144] = r6;
    l4[t + 7168] = r7;
    l4[t + 8192] = r8;
    if (tail) l4[t + 9216] = r9;
    __syncthreads();

    // ---- box loop: 4 boxes in flight, wave-uniform sub ----
    int b0 = starts[a], b1 = starts[a + 1];
    int sub = t >> 8;             // 0..3, uniform per wave
    int q   = t & 255;            // pixel-quad within box
    int y   = q >> 3;             // 0..31
    int xg  = (q & 7) << 2;       // 0,4,...,28

    for (int b = b0; b < b1; b += 4) {
        int bb = b + sub;
        if (bb < b1) {            // wave-uniform branch
            unsigned int v = keys[bb];
            int y0 = (v >> 17) & 255;
            int x0 = (v >> 9) & 255;
            int i  = (int)(v & 511u);
            const float* p = lds + (y0 + y) * W_ + (x0 + xg);
            v4f vv;
            vv[0] = p[0];
            vv[1] = p[1];
            vv[2] = p[2];
            vv[3] = p[3];
            v4f* dst = (v4f*)(out + (((size_t)i << 18) + ((size_t)c << 10) + (size_t)(q << 2)));
            __builtin_nontemporal_store(vv, dst);
        }
    }
}

extern "C" void kernel_launch(void* const* d_in, const int* in_sizes, int n_in,
                              void* d_out, int out_size, void* d_ws, size_t ws_size,
                              hipStream_t stream) {
    const float* fm    = (const float*)d_in[0];
    const int*   boxes = (const int*)d_in[1];
    const int*   assoc = (const int*)d_in[2];
    float*       out   = (float*)d_out;

    unsigned int* keys   = (unsigned int*)d_ws;        // 512 u32
    int*          starts = (int*)d_ws + N_;            // 9 ints

    // allow 160,000 B dynamic LDS (host-side attribute set; idempotent, no stream op)
    (void)hipFuncSetAttribute((const void*)roicut_kernel,
                              hipFuncAttributeMaxDynamicSharedMemorySize,
                              PLANE * (int)sizeof(float));

    sort_boxes_kernel<<<1, N_, 0, stream>>>(boxes, assoc, keys, starts);

    int grid = B_ * C_;   // 2048 blocks: one per (sample, channel) plane
    roicut_kernel<<<grid, 1024, PLANE * sizeof(float), stream>>>(fm, keys, starts, out);
}

// Round 5
// 172.493 us; speedup vs baseline: 1.2507x; 1.0050x over previous
//
#include <hip/hip_runtime.h>

// RoiCut: out[i, c, y, x] = fm[assoc[i], c, y0_i + y, x0_i + x]
// fm: [8, 256, 200, 200] fp32, boxes_yx: [512, 2] int32 (y0, x0), assoc: [512] int32
// out: [512, 256, 32, 32] fp32
//
// R4 strategy: keep R3's structural exact-once reads, add phase overlap.
//  - block = (sample, channel, half-plane): 100 rows = 80,000 B LDS
//    -> 2 blocks/CU resident (vs 1 in R3): one block's store phase overlaps the
//       other's staging + barrier drain; finer grid halves imbalance quantum.
//  - reads stay exact-once & perfectly coalesced (each (a,c,h) slice read by
//    exactly one block; no inter-block reuse exists -> caches irrelevant).
//  - boxes straddling the row-100 boundary are written partially by each half
//    (predicated rows); work conserved.
//  - non-temporal stores; sort kernel groups boxes by sample.

typedef float v4f __attribute__((ext_vector_type(4)));

constexpr int C_     = 256;
constexpr int H_     = 200;
constexpr int W_     = 200;
constexpr int BOX_   = 32;
constexpr int N_     = 512;
constexpr int B_     = 8;
constexpr int PLANE  = H_ * W_;       // 40000 floats
constexpr int HROWS  = 100;           // rows per half
constexpr int HLDS   = HROWS * W_;    // 20000 floats = 80,000 B
constexpr int HLDS4  = HLDS / 4;      // 5000 float4

__global__ __launch_bounds__(512) void sort_boxes_kernel(
    const int* __restrict__ boxes,
    const int* __restrict__ assoc,
    unsigned int* __restrict__ keys,
    int* __restrict__ starts)
{
    __shared__ unsigned int key[N_];
    int t = threadIdx.x;  // 512 threads, one per box

    int y0 = boxes[2 * t];
    int x0 = boxes[2 * t + 1];
    y0 = min(max(y0, 0), H_ - BOX_);
    x0 = min(max(x0, 0), W_ - BOX_);
    unsigned int a = (unsigned int)assoc[t];
    // key: [assoc:3 | y0:8 | x0:8 | idx:9] -- unique -> deterministic sort
    key[t] = (a << 25) | ((unsigned int)y0 << 17) | ((unsigned int)x0 << 9) | (unsigned int)t;
    __syncthreads();

    for (int k = 2; k <= N_; k <<= 1) {
        for (int j = k >> 1; j > 0; j >>= 1) {
            int ixj = t ^ j;
            if (ixj > t) {
                unsigned int va = key[t], vb = key[ixj];
                bool asc = ((t & k) == 0);
                if ((va > vb) == asc) { key[t] = vb; key[ixj] = va; }
            }
            __syncthreads();
        }
    }

    unsigned int v = key[t];
    keys[t] = v;
    int at = (int)(v >> 25);
    int ap = (t == 0) ? -1 : (int)(key[t - 1] >> 25);
    for (int aa = ap + 1; aa <= at; ++aa) starts[aa] = t;           // handles empty samples
    if (t == N_ - 1) for (int aa = at + 1; aa <= B_; ++aa) starts[aa] = N_;
}

__global__ __launch_bounds__(1024, 8) void roicut_kernel(
    const float* __restrict__ fm,
    const unsigned int* __restrict__ keys,
    const int* __restrict__ starts,
    float* __restrict__ out)
{
    extern __shared__ float lds[];   // 80,000 B = half plane (100 rows x 200)

    int bid = blockIdx.x;
    int h = bid & 1;                 // half: rows [100h, 100h+100)
    int c = (bid >> 1) & 255;        // channel
    int a = bid >> 9;                // sample
    int t = threadIdx.x;             // 1024 threads

    // ---- stage half plane into LDS, perfectly coalesced, exact-once ----
    const v4f* src = (const v4f*)(fm + (size_t)(a * C_ + c) * PLANE) + h * HLDS4;
    v4f* l4 = (v4f*)lds;
    v4f r0 = src[t];
    v4f r1 = src[t + 1024];
    v4f r2 = src[t + 2048];
    v4f r3 = src[t + 3072];
    bool tail = t < (HLDS4 - 4096);   // t < 904
    v4f r4;
    if (tail) r4 = src[t + 4096];
    l4[t]        = r0;
    l4[t + 1024] = r1;
    l4[t + 2048] = r2;
    l4[t + 3072] = r3;
    if (tail) l4[t + 4096] = r4;
    __syncthreads();

    // ---- box loop: 4 boxes in flight (sub = 4 waves each) ----
    int b0 = starts[a], b1 = starts[a + 1];
    int sub = t >> 8;             // 0..3
    int q   = t & 255;            // pixel-quad within box tile
    int y   = q >> 3;             // 0..31
    int xg  = (q & 7) << 2;       // 0,4,...,28
    int hbase = h * HROWS;        // first plane row owned by this half

    for (int b = b0; b < b1; b += 4) {
        int bb = b + sub;
        if (bb < b1) {
            unsigned int v = keys[bb];
            int y0 = (v >> 17) & 255;
            int x0 = (v >> 9) & 255;
            int i  = (int)(v & 511u);
            int ly = y0 + y - hbase;          // row within this half
            if (ly >= 0 && ly < HROWS) {      // predicated rows (straddling boxes)
                const float* p = lds + ly * W_ + (x0 + xg);
                v4f vv;
                vv[0] = p[0];
                vv[1] = p[1];
                vv[2] = p[2];
                vv[3] = p[3];
                v4f* dst = (v4f*)(out + (((size_t)i << 18) + ((size_t)c << 10) + (size_t)(q << 2)));
                __builtin_nontemporal_store(vv, dst);
            }
        }
    }
}

extern "C" void kernel_launch(void* const* d_in, const int* in_sizes, int n_in,
                              void* d_out, int out_size, void* d_ws, size_t ws_size,
                              hipStream_t stream) {
    const float* fm    = (const float*)d_in[0];
    const int*   boxes = (const int*)d_in[1];
    const int*   assoc = (const int*)d_in[2];
    float*       out   = (float*)d_out;

    unsigned int* keys   = (unsigned int*)d_ws;        // 512 u32
    int*          starts = (int*)d_ws + N_;            // 9 ints

    // allow 80,000 B dynamic LDS (host-side attribute; idempotent, no stream op)
    (void)hipFuncSetAttribute((const void*)roicut_kernel,
                              hipFuncAttributeMaxDynamicSharedMemorySize,
                              HLDS * (int)sizeof(float));

    sort_boxes_kernel<<<1, N_, 0, stream>>>(boxes, assoc, keys, starts);

    int grid = B_ * C_ * 2;   // 4096 blocks: one per (sample, channel, half)
    roicut_kernel<<<grid, 1024, HLDS * sizeof(float), stream>>>(fm, keys, starts, out);
}